// Round 6
// baseline (187.057 us; speedup 1.0000x reference)
//
#include <hip/hip_runtime.h>
#include <cstdint>

// CrossLayerAttention on MI355X (gfx950).  B=4 S=1024 H=2048 NH=16 HD=128.
// R6: attention rebuilt on 32x32x16 MFMA + swapped QK^T + in-register softmax
//     (T12): 32 q-rows/wave doubles FLOP per LDS byte, P never touches LDS.
//     2-wave blocks, BQ=64, balanced pairs {j,15-j}, 2 blocks/CU.

typedef unsigned short u16;
typedef __bf16 bf16x8 __attribute__((ext_vector_type(8)));
typedef float  f32x4  __attribute__((ext_vector_type(4)));
typedef float  f32x16 __attribute__((ext_vector_type(16)));
typedef uint32_t u32x4 __attribute__((ext_vector_type(4)));

__device__ __forceinline__ u16 f2bf(float f) {
  uint32_t u = __builtin_bit_cast(uint32_t, f);
  u += 0x7fffu + ((u >> 16) & 1u);   // RNE; inputs finite
  return (u16)(u >> 16);
}
__device__ __forceinline__ float bf2f(u16 h) {
  uint32_t u = ((uint32_t)h) << 16;
  return __builtin_bit_cast(float, u);
}
__device__ __forceinline__ uint32_t pkbf(float a, float b) {
  return (uint32_t)f2bf(a) | ((uint32_t)f2bf(b) << 16);
}
__device__ __forceinline__ void gld16(const void* g, void* l) {
  __builtin_amdgcn_global_load_lds(
      (const __attribute__((address_space(1))) void*)g,
      (__attribute__((address_space(3))) void*)l, 16, 0, 0);
}

// ---------------- fp32 -> bf16 convert ----------------
__global__ __launch_bounds__(256) void cvt_kernel(const float* __restrict__ in,
                                                  u16* __restrict__ out, int n4) {
  int i = blockIdx.x * 256 + threadIdx.x;
  if (i < n4) {
    float4 v = ((const float4*)in)[i];
    ushort4 o;
    o.x = f2bf(v.x); o.y = f2bf(v.y); o.z = f2bf(v.z); o.w = f2bf(v.w);
    ((ushort4*)out)[i] = o;
  }
}

// ---------------- per-bh transpose + cvt: out[c][r] = bf16(in[r][c]) ----------------
__global__ __launch_bounds__(256) void transpose_cvt(const float* __restrict__ in,
                                                     u16* __restrict__ out, int R, int C) {
  __shared__ float tile[32][33];
  const int bh = blockIdx.x;
  const int nct = C >> 5;
  const int rt = blockIdx.y / nct, ct = blockIdx.y % nct;
  const float* src = in + (size_t)bh * R * C;
  u16* dst = out + (size_t)bh * R * C;
  const int r = threadIdx.x >> 3, c4 = (threadIdx.x & 7) * 4;
  float4 v = *(const float4*)(src + (size_t)(rt * 32 + r) * C + ct * 32 + c4);
  tile[r][c4 + 0] = v.x; tile[r][c4 + 1] = v.y;
  tile[r][c4 + 2] = v.z; tile[r][c4 + 3] = v.w;
  __syncthreads();
  ushort4 o;
  o.x = f2bf(tile[c4 + 0][r]); o.y = f2bf(tile[c4 + 1][r]);
  o.z = f2bf(tile[c4 + 2][r]); o.w = f2bf(tile[c4 + 3][r]);
  *(ushort4*)(dst + (size_t)(ct * 32 + r) * R + rt * 32 + c4) = o;
}

// ---------------- GEMM (out-proj): C[M,N] = A[M,K] @ B[N,K]^T + bias ----------------
template<bool OUT_BF16>
__global__ __launch_bounds__(256, 2)
void gemm_bt(const u16* __restrict__ A, const u16* __restrict__ Bm,
             const float* __restrict__ bias, void* __restrict__ Cout,
             int M, int N, int K) {
  __shared__ __align__(16) u16 As[128 * 32];
  __shared__ __align__(16) u16 Bs[128 * 32];
  const int t = threadIdx.x, lane = t & 63, w = t >> 6;
  const int row0 = blockIdx.x * 128, col0 = blockIdx.y * 128;
  const int wr = (w >> 1) * 64, wc = (w & 1) * 64;
  const int fr = lane & 15, fg = lane >> 4, fk = fg * 8;
  const int srow = w * 32 + (lane >> 2), scol = (lane & 3) * 8;
  const u16* gA0 = A  + (size_t)(row0 + srow) * K + scol;
  const u16* gB0 = Bm + (size_t)(col0 + srow) * K + scol;
  u16* lA0 = As + (w * 32) * 32;
  u16* lA1 = As + (w * 32 + 16) * 32;
  u16* lB0 = Bs + (w * 32) * 32;
  u16* lB1 = Bs + (w * 32 + 16) * 32;
  f32x4 acc[4][4] = {};

  for (int k0 = 0; k0 < K; k0 += 32) {
    __syncthreads();
    gld16(gA0 + k0, lA0);
    gld16(gA0 + k0 + (size_t)16 * K, lA1);
    gld16(gB0 + k0, lB0);
    gld16(gB0 + k0 + (size_t)16 * K, lB1);
    __syncthreads();
    bf16x8 af[4], bq[4];
#pragma unroll
    for (int i = 0; i < 4; i++) af[i] = *(const bf16x8*)&As[(wr + i * 16 + fr) * 32 + fk];
#pragma unroll
    for (int i = 0; i < 4; i++) bq[i] = *(const bf16x8*)&Bs[(wc + i * 16 + fr) * 32 + fk];
#pragma unroll
    for (int mi = 0; mi < 4; mi++)
#pragma unroll
      for (int ni = 0; ni < 4; ni++)
        acc[mi][ni] = __builtin_amdgcn_mfma_f32_16x16x32_bf16(af[mi], bq[ni], acc[mi][ni], 0, 0, 0);
  }

#pragma unroll
  for (int mi = 0; mi < 4; mi++)
#pragma unroll
    for (int ni = 0; ni < 4; ni++) {
      int col = col0 + wc + ni * 16 + fr;
      float bv = bias[col];
#pragma unroll
      for (int i = 0; i < 4; i++) {
        int row = row0 + wr + mi * 16 + fg * 4 + i;
        float v = acc[mi][ni][i] + bv;
        if constexpr (OUT_BF16) ((u16*)Cout)[(size_t)row * N + col] = f2bf(v);
        else                    ((float*)Cout)[(size_t)row * N + col] = v;
      }
    }
}

// ---------------- Q-proj GEMM + fused RoPE, 2x2 wave tiling ----------------
__global__ __launch_bounds__(256, 2)
void gemm_rope(const u16* __restrict__ A, const u16* __restrict__ Bm,
               const float* __restrict__ bias, const float* __restrict__ cosb,
               const float* __restrict__ sinb, u16* __restrict__ qout) {
  __shared__ __align__(16) u16 As[128 * 32];
  __shared__ __align__(16) u16 Bs[128 * 32];
  const int K = 2048;
  const int t = threadIdx.x, lane = t & 63, w = t >> 6;
  const int row0 = blockIdx.x * 128, h = blockIdx.y;
  const int wr = (w >> 1) * 64, g = w & 1;
  const int fr = lane & 15, fg = lane >> 4, fk = fg * 8;
  const int srow = w * 32 + (lane >> 2), scol = (lane & 3) * 8;
  const u16* gA0 = A  + (size_t)(row0 + srow) * K + scol;
  const u16* gB0 = Bm + (size_t)(h * 128 + srow) * K + scol;
  u16* lA0 = As + (w * 32) * 32;
  u16* lA1 = As + (w * 32 + 16) * 32;
  u16* lB0 = Bs + (w * 32) * 32;
  u16* lB1 = Bs + (w * 32 + 16) * 32;
  f32x4 acc[4][4] = {};
  const int colr[4] = {g * 32 + fr, g * 32 + 16 + fr,
                       g * 32 + 64 + fr, g * 32 + 80 + fr};

  for (int k0 = 0; k0 < K; k0 += 32) {
    __syncthreads();
    gld16(gA0 + k0, lA0);
    gld16(gA0 + k0 + (size_t)16 * K, lA1);
    gld16(gB0 + k0, lB0);
    gld16(gB0 + k0 + (size_t)16 * K, lB1);
    __syncthreads();
    bf16x8 af[4], bq[4];
#pragma unroll
    for (int i = 0; i < 4; i++) af[i] = *(const bf16x8*)&As[(wr + i * 16 + fr) * 32 + fk];
#pragma unroll
    for (int ni = 0; ni < 4; ni++) bq[ni] = *(const bf16x8*)&Bs[colr[ni] * 32 + fk];
#pragma unroll
    for (int mi = 0; mi < 4; mi++)
#pragma unroll
      for (int ni = 0; ni < 4; ni++)
        acc[mi][ni] = __builtin_amdgcn_mfma_f32_16x16x32_bf16(af[mi], bq[ni], acc[mi][ni], 0, 0, 0);
  }

  float bv[4];
#pragma unroll
  for (int ni = 0; ni < 4; ni++) bv[ni] = bias[h * 128 + colr[ni]];
#pragma unroll
  for (int mi = 0; mi < 4; mi++)
#pragma unroll
    for (int i = 0; i < 4; i++) {
      int row = row0 + wr + mi * 16 + fg * 4 + i;     // b*1024 + s
      int s = row & 1023, bb = row >> 10;
      size_t obase = (((size_t)(bb * 16 + h)) * 1024 + s) * 128;
#pragma unroll
      for (int dp = 0; dp < 2; dp++) {
        int d = g * 32 + dp * 16 + fr;                 // 0..63
        float c  = cosb[s * 128 + d];
        float sn = sinb[s * 128 + d];
        float qlo = acc[mi][dp][i] + bv[dp];
        float qhi = acc[mi][dp + 2][i] + bv[dp + 2];
        qout[obase + d]      = f2bf(qlo * c - qhi * sn);
        qout[obase + d + 64] = f2bf(qhi * c + qlo * sn);
      }
    }
}

// ---------------- Flash attention: 32x32 MFMA, in-register softmax ----------------
// 512 blocks x 128 thr (2 waves, 32 q-rows each -> BQ=64). Block x: bh=x&63,
// jp=x>>6; q-tile pair {jp, 15-jp} -> uniform 17 kv-tiles (BKV=64).
// Swapped QK^T: sa = mfma(A=K, B=Q) => lane holds S[q=lane&31][16 kv vals],
// partner lane (^32) holds the other 16. Softmax fully in-register (one
// shfl_xor(32) per reduce). P repacked to bf16 A-frags in-register (T12),
// PV B-frags from vT[d][s] LDS tile. K[64][128]/V[128][64] double-buffered,
// XOR-swizzled (rule #21), staged via global_load_lds.
__global__ __launch_bounds__(128, 1)
void attn_kernel(const u16* __restrict__ qbf, const u16* __restrict__ kTb,
                 const u16* __restrict__ vTb, u16* __restrict__ aout) {
  __shared__ __align__(16) u16 Kb[2][64 * 128];   // 2 x 16 KB
  __shared__ __align__(16) u16 Vb[2][128 * 64];   // 2 x 16 KB
  const int t = threadIdx.x, lane = t & 63, w = t >> 6;   // w in 0..1
  const int x = blockIdx.x;
  const int bh = x & 63, jp = x >> 6;
  const int b = bh >> 4, h = bh & 15;
  const int q31 = lane & 31, hi = lane >> 5, kx = lane & 7;
  const float scale = 0.088388347648318447f;      // 1/sqrt(128)
  const u16* kbase = kTb + (size_t)bh * 131072;   // [s][d]
  const u16* vbase = vTb + (size_t)bh * 131072;   // [d][s]

  // staging geometry (source col pre-swizzled, linear LDS dest; key = row&7)
  const int kR = t >> 4;                           // K src row base (0..7)
  const int kG = ((t & 15) ^ (kR & 7)) * 8;
  const int vR = t >> 3;                           // V src row base (0..15)
  const int vG = ((t & 7) ^ (vR & 7)) * 8;

  for (int pass = 0; pass < 2; pass++) {
    const int j = pass ? 15 - jp : jp;
    const int q0 = j * 64;
    const int rw0 = q0 + w * 32;                   // wave's first q-row
    const int rowg = rw0 + q31;                    // this lane's q-row
    const int ntiles = j + 1;

    // Q fragments: qf[ds] = Q[rowg][ds*16 + hi*8 .. +8]   (32 VGPR)
    bf16x8 qf[8];
#pragma unroll
    for (int ds = 0; ds < 8; ds++)
      qf[ds] = *(const bf16x8*)&qbf[((size_t)bh * 1024 + rowg) * 128 + ds * 16 + hi * 8];

    f32x16 acc[4] = {};
    float m = -3e38f, l = 0.f;

    auto STAGE = [&](int kt, int buf) {
      const u16* ksrc = kbase + (size_t)(kt * 64 + kR) * 128 + kG;
      const u16* vsrc = vbase + (size_t)vR * 1024 + kt * 64 + vG;
      u16* kl = &Kb[buf][t * 8];
      u16* vl = &Vb[buf][t * 8];
#pragma unroll
      for (int p = 0; p < 8; p++) {
        gld16(ksrc + (size_t)p * 8 * 128, kl + p * 1024);
        gld16(vsrc + (size_t)p * 16 * 1024, vl + p * 1024);
      }
    };

    STAGE(0, 0);
    __syncthreads();
    int cur = 0;
    for (int kt = 0; kt < ntiles; kt++) {
      if (kt + 1 < ntiles) STAGE(kt + 1, cur ^ 1);

      // ---- QK^T (swapped): sa0/sa1 = S^T for kv 0..31 / 32..63 ----
      f32x16 sa0 = {}, sa1 = {};
      __builtin_amdgcn_s_setprio(1);
#pragma unroll
      for (int ds = 0; ds < 8; ds++) {
        bf16x8 k0 = *(const bf16x8*)&Kb[cur][q31 * 128 + (((ds * 2 + hi) ^ kx) * 8)];
        bf16x8 k1 = *(const bf16x8*)&Kb[cur][(q31 + 32) * 128 + (((ds * 2 + hi) ^ kx) * 8)];
        sa0 = __builtin_amdgcn_mfma_f32_32x32x16_bf16(k0, qf[ds], sa0, 0, 0, 0);
        sa1 = __builtin_amdgcn_mfma_f32_32x32x16_bf16(k1, qf[ds], sa1, 0, 0, 0);
      }
      __builtin_amdgcn_s_setprio(0);

      // ---- in-register softmax (lane owns row q31; partner = lane^32) ----
      const bool diag = (kt * 64 + 63 > rw0);
      float mx = -3e38f;
#pragma unroll
      for (int r = 0; r < 16; r++) {
        float s0 = sa0[r] * scale;
        float s1 = sa1[r] * scale;
        if (diag) {
          int cr = (r & 3) + 8 * (r >> 2) + 4 * hi;
          if (kt * 64 + cr > rowg)      s0 = -1e9f;
          if (kt * 64 + 32 + cr > rowg) s1 = -1e9f;
        }
        sa0[r] = s0; sa1[r] = s1;
        mx = fmaxf(mx, fmaxf(s0, s1));
      }
      mx = fmaxf(mx, __shfl_xor(mx, 32));
      if (!__all(mx - m <= 8.f)) {                 // defer-max (T13)
        float mn = fmaxf(m, mx);
        float corr = __expf(m - mn);
        m = mn; l *= corr;
#pragma unroll
        for (int nd = 0; nd < 4; nd++)
#pragma unroll
          for (int r = 0; r < 16; r++) acc[nd][r] *= corr;
      }
      float sum = 0.f;
#pragma unroll
      for (int r = 0; r < 16; r++) {
        float p0 = __expf(sa0[r] - m); sa0[r] = p0;
        float p1 = __expf(sa1[r] - m); sa1[r] = p1;
        sum += p0 + p1;
      }
      sum += __shfl_xor(sum, 32);
      l += sum;

      // ---- P -> bf16 A-frags in-register (T12) + PV ----
      __builtin_amdgcn_s_setprio(1);
#pragma unroll
      for (int ks = 0; ks < 4; ks++) {
        const int r0 = (ks & 1) * 8;
        float p0 = (ks < 2) ? sa0[r0 + 0] : sa1[r0 + 0];
        float p1 = (ks < 2) ? sa0[r0 + 1] : sa1[r0 + 1];
        float p2 = (ks < 2) ? sa0[r0 + 2] : sa1[r0 + 2];
        float p3 = (ks < 2) ? sa0[r0 + 3] : sa1[r0 + 3];
        float p4 = (ks < 2) ? sa0[r0 + 4] : sa1[r0 + 4];
        float p5 = (ks < 2) ? sa0[r0 + 5] : sa1[r0 + 5];
        float p6 = (ks < 2) ? sa0[r0 + 6] : sa1[r0 + 6];
        float p7 = (ks < 2) ? sa0[r0 + 7] : sa1[r0 + 7];
        uint32_t w0 = pkbf(p0, p1), w1 = pkbf(p2, p3);
        uint32_t w2 = pkbf(p4, p5), w3 = pkbf(p6, p7);
        uint32_t x0 = __shfl_xor(w0, 32), x1 = __shfl_xor(w1, 32);
        uint32_t x2 = __shfl_xor(w2, 32), x3 = __shfl_xor(w3, 32);
        u32x4 aw;
        aw.x = hi ? x2 : w0;
        aw.y = hi ? x3 : w1;
        aw.z = hi ? w2 : x0;
        aw.w = hi ? w3 : x1;
        bf16x8 af = __builtin_bit_cast(bf16x8, aw);
#pragma unroll
        for (int nd = 0; nd < 4; nd++) {
          bf16x8 vf = *(const bf16x8*)&Vb[cur][(nd * 32 + q31) * 64 + (((ks * 2 + hi) ^ kx) * 8)];
          acc[nd] = __builtin_amdgcn_mfma_f32_32x32x16_bf16(af, vf, acc[nd], 0, 0, 0);
        }
      }
      __builtin_amdgcn_s_setprio(0);

      __syncthreads();                             // next tile staged; reads done
      cur ^= 1;
    }

    // ---- epilogue: O[q][d] rows crow(r,hi), cols nd*32+q31 ----
    float linv = 1.f / l;
#pragma unroll
    for (int r = 0; r < 16; r++) {
      int cr = (r & 3) + 8 * (r >> 2) + 4 * hi;
      float li = __shfl(linv, cr);                 // lane cr holds row cr's l
      int sg = q0 + w * 32 + cr;
      size_t obase = (((size_t)b * 1024 + sg) * 16 + h) * 128 + q31;
#pragma unroll
      for (int nd = 0; nd < 4; nd++)
        aout[obase + nd * 32] = f2bf(acc[nd][r] * li);
    }
  }
}

// ---------------- launcher ----------------
extern "C" void kernel_launch(void* const* d_in, const int* in_sizes, int n_in,
                              void* d_out, int out_size, void* d_ws, size_t ws_size,
                              hipStream_t stream) {
  const float* hs  = (const float*)d_in[0];
  const float* key = (const float*)d_in[1];
  const float* val = (const float*)d_in[2];
  // d_in[3]: attention_mask — causal, reproduced analytically
  const float* rc  = (const float*)d_in[4];
  const float* rs  = (const float*)d_in[5];
  const float* wq  = (const float*)d_in[6];
  const float* bq  = (const float*)d_in[7];
  const float* wo  = (const float*)d_in[8];
  const float* bo  = (const float*)d_in[9];
  float* out = (float*)d_out;

  char* ws = (char*)d_ws;
  u16* hs_bf = (u16*)(ws);                   // 16 MB ; reused as attn_bf
  u16* wq_bf = (u16*)(ws + 16777216);        //  8 MB
  u16* wo_bf = (u16*)(ws + 25165824);        //  8 MB
  u16* q_bf  = (u16*)(ws + 33554432);        // 16 MB
  u16* kT    = (u16*)(ws + 50331648);        // 16 MB  [bh][s][d]
  u16* vT    = (u16*)(ws + 67108864);        // 16 MB  [bh][d][s]
  u16* attn_bf = hs_bf;                      // hs_bf dead after gemm_rope

  cvt_kernel<<<8192, 256, 0, stream>>>(hs, hs_bf, 8388608 / 4);
  cvt_kernel<<<4096, 256, 0, stream>>>(wq, wq_bf, 4194304 / 4);
  cvt_kernel<<<4096, 256, 0, stream>>>(wo, wo_bf, 4194304 / 4);

  transpose_cvt<<<dim3(64, 128), 256, 0, stream>>>(key, kT, 128, 1024);   // -> kT[bh][s][d]
  transpose_cvt<<<dim3(64, 128), 256, 0, stream>>>(val, vT, 1024, 128);   // -> vT[bh][d][s]

  gemm_rope<<<dim3(32, 16), 256, 0, stream>>>(hs_bf, wq_bf, bq, rc, rs, q_bf);
  attn_kernel<<<512, 128, 0, stream>>>(q_bf, kT, vT, attn_bf);
  gemm_bt<false><<<dim3(32, 16), 256, 0, stream>>>(attn_bf, wo_bf, bo, out, 4096, 2048, 2048);
}